// Round 8
// baseline (977.608 us; speedup 1.0000x reference)
//
#include <hip/hip_runtime.h>
#include <hip/hip_bf16.h>
#include <hip/hip_cooperative_groups.h>

namespace cg = cooperative_groups;

#define NEG_SLOPE 0.2f
#define LOG2E 1.4426950408889634f
// s_getreg imm: (size-1)<<11 | offset<<6 | id ; HW_REG_XCC_ID = 20 (CDNA3/4)
#define HWREG_XCC_ID_FULL (((32 - 1) << 11) | (0 << 6) | 20)

#define CSR_GRID 1024

typedef _Float16 f16;
typedef f16 f16x8 __attribute__((ext_vector_type(8)));
typedef float f32x4 __attribute__((ext_vector_type(4)));

__device__ __forceinline__ unsigned pack_h2(float a, float b) {
    union { f16 h[2]; unsigned u; } c;
    c.h[0] = (f16)a; c.h[1] = (f16)b;
    return c.u;
}

// ================= cooperative CSR mega-kernel =================
// phase 0: int64-detect flag + weight transpose + deg_part memset
// phase 1: XCD-sharded degree histogram (4 edges/thread, packed rank)
// phase 2: 3-level exclusive scan (thread->wave->block->grid)
// phase 3: scatter into csr_src
// grid = CSR_GRID x 256, no heavy LDS -> co-residency guaranteed (4 blk/CU).
__global__ __launch_bounds__(256) void k_csr(const int* __restrict__ ei32,
                                             const void* __restrict__ ei,
                                             int* __restrict__ flag,
                                             const float* __restrict__ W1,
                                             const float* __restrict__ W2,
                                             f16* __restrict__ W1t,
                                             f16* __restrict__ W2t,
                                             int* __restrict__ deg_part,
                                             unsigned* __restrict__ packed,
                                             int* __restrict__ offsets,
                                             int* __restrict__ blksum,
                                             int* __restrict__ blkoff,
                                             int* __restrict__ csr_src,
                                             int N, int E) {
    cg::grid_group grid = cg::this_grid();
    __shared__ int wsums[4];
    __shared__ int found;
    const int B = blockIdx.x, t = threadIdx.x;
    const int gsize = gridDim.x * blockDim.x;          // CSR_GRID*256
    const int gid = B * blockDim.x + t;
    const int lane = t & 63, wid = t >> 6;

    // ---- phase 0 ----
    if (B == 0) {
        if (t == 0) found = 0;
        __syncthreads();
        for (int i = t; i < 1024; i += 256)
            if (ei32[2 * i + 1] != 0) found = 1;
        __syncthreads();
        if (t == 0) *flag = found ? 0 : 1;             // 1 => int64
    }
    for (int o = gid; o < 128 * 128 + 48 * 128; o += gsize) {
        if (o < 128 * 128) {
            int n = o >> 7, k = o & 127;
            W1t[o] = (f16)W1[k * 128 + n];
        } else {
            int o2 = o - 128 * 128;
            int n = o2 >> 7, k = o2 & 127;
            W2t[o2] = (f16)(n < 40 ? W2[k * 40 + n] : 0.f);
        }
    }
    {
        uint4* dp4 = (uint4*)deg_part;
        for (int i = gid; i < 2 * N; i += gsize) dp4[i] = (uint4){0, 0, 0, 0};
    }
    grid.sync();

    // ---- phase 1: degree histogram ----
    const int f64 = *flag;
    const int xcc = (int)(__builtin_amdgcn_s_getreg(HWREG_XCC_ID_FULL) & 7u);
    for (int base = gid * 4; base < E; base += gsize * 4) {
        int dv[4];
        if (f64) {
            const long long* p = (const long long*)ei + E;
#pragma unroll
            for (int k = 0; k < 4; k++) dv[k] = (base + k < E) ? (int)p[base + k] : 0;
        } else {
            const int* p = (const int*)ei + E;
#pragma unroll
            for (int k = 0; k < 4; k++) dv[k] = (base + k < E) ? p[base + k] : 0;
        }
#pragma unroll
        for (int k = 0; k < 4; k++) {
            if (base + k < E) {
                int lr = atomicAdd(&deg_part[xcc * N + dv[k]], 1);
                packed[base + k] = ((unsigned)dv[k] << 15) | ((unsigned)xcc << 12) |
                                   (unsigned)lr;
            }
        }
    }
    grid.sync();

    // ---- phase 2a: shard prefix + thread/wave/block scan ----
    // each thread owns 4 consecutive nodes (grid covers up to 1,048,576 nodes)
    const int idx = gid * 4;
    int v0 = 0, v1 = 0, v2 = 0, v3 = 0;
    if (((N & 3) == 0) && (idx + 3 < N)) {
        uint4 u[8];
#pragma unroll
        for (int x = 0; x < 8; x++) u[x] = *(uint4*)&deg_part[x * N + idx];
        int p0 = 0, p1 = 0, p2 = 0, p3 = 0;
#pragma unroll
        for (int x = 0; x < 8; x++) {
            uint4 w = u[x];
            u[x] = (uint4){(unsigned)p0, (unsigned)p1, (unsigned)p2, (unsigned)p3};
            p0 += (int)w.x; p1 += (int)w.y; p2 += (int)w.z; p3 += (int)w.w;
        }
#pragma unroll
        for (int x = 0; x < 8; x++) *(uint4*)&deg_part[x * N + idx] = u[x];
        v0 = p0; v1 = p1; v2 = p2; v3 = p3;
    } else if (idx < N) {
        int vv[4] = {0, 0, 0, 0};
        for (int i = 0; i < 4; i++) {
            int d = idx + i;
            if (d >= N) break;
            int p = 0;
#pragma unroll
            for (int x = 0; x < 8; x++) {
                int t0 = deg_part[x * N + d];
                deg_part[x * N + d] = p;
                p += t0;
            }
            vv[i] = p;
        }
        v0 = vv[0]; v1 = vv[1]; v2 = vv[2]; v3 = vv[3];
    }
    const int s1 = v0 + v1, s2 = s1 + v2, s3 = s2 + v3;
    int inc = s3;
#pragma unroll
    for (int off = 1; off < 64; off <<= 1) {
        int y = __shfl_up(inc, off);
        if (lane >= off) inc += y;
    }
    if (lane == 63) wsums[wid] = inc;
    __syncthreads();
    if (wid == 0) {
        int v = (lane < 4) ? wsums[lane] : 0;
        int wi = v;
#pragma unroll
        for (int off = 1; off < 4; off <<= 1) {
            int y = __shfl_up(wi, off);
            if (lane >= off) wi += y;
        }
        if (lane < 4) wsums[lane] = wi - v;
        if (lane == 3) blksum[B] = wi;
    }
    __syncthreads();
    const int excl_local = wsums[wid] + (inc - s3);    // saved in register
    grid.sync();

    // ---- phase 2b: block 0 scans the CSR_GRID block sums -> blkoff ----
    if (B == 0) {
        int i = t * 4;                                  // covers CSR_GRID exactly
        int b0 = blksum[i], b1 = blksum[i + 1], b2 = blksum[i + 2], b3 = blksum[i + 3];
        int t1 = b0 + b1, t2 = t1 + b2, t3 = t2 + b3;
        int inc2 = t3;
#pragma unroll
        for (int off = 1; off < 64; off <<= 1) {
            int y = __shfl_up(inc2, off);
            if (lane >= off) inc2 += y;
        }
        if (lane == 63) wsums[wid] = inc2;
        __syncthreads();
        if (wid == 0) {
            int v = (lane < 4) ? wsums[lane] : 0;
            int wi = v;
#pragma unroll
            for (int off = 1; off < 4; off <<= 1) {
                int y = __shfl_up(wi, off);
                if (lane >= off) wi += y;
            }
            if (lane < 4) wsums[lane] = wi - v;
        }
        __syncthreads();
        int ex2 = wsums[wid] + (inc2 - t3);
        blkoff[i] = ex2;
        blkoff[i + 1] = ex2 + b0;
        blkoff[i + 2] = ex2 + t1;
        blkoff[i + 3] = ex2 + t2;
    }
    grid.sync();

    // ---- phase 2c: write offsets ----
    {
        const int boff = blkoff[B] + excl_local;
        if (idx + 0 < N) offsets[idx + 1] = boff + v0;
        if (idx + 1 < N) offsets[idx + 2] = boff + s1;
        if (idx + 2 < N) offsets[idx + 3] = boff + s2;
        if (idx + 3 < N) offsets[idx + 4] = boff + s3;
        if (gid == 0) offsets[0] = 0;
    }
    grid.sync();

    // ---- phase 3: scatter ----
    for (int base = gid * 4; base < E; base += gsize * 4) {
        int sv[4];
        if (f64) {
            const long long* p = (const long long*)ei;
#pragma unroll
            for (int k = 0; k < 4; k++) sv[k] = (base + k < E) ? (int)p[base + k] : 0;
        } else {
            const int* p = (const int*)ei;
#pragma unroll
            for (int k = 0; k < 4; k++) sv[k] = (base + k < E) ? p[base + k] : 0;
        }
#pragma unroll
        for (int k = 0; k < 4; k++) {
            if (base + k < E) {
                unsigned u = packed[base + k];
                int d = (int)(u >> 15);
                int xc = (int)((u >> 12) & 7u);
                int lr = (int)(u & 0xFFFu);
                csr_src[offsets[d] + deg_part[xc * N + d] + lr] = sv[k];
            }
        }
    }
}

// ---------------- GEMM1 (MFMA f16) + fused attn1 dots ----------------
// Af = (f16)(X @ W1) [N][128]; aS1/aD1[n*4+h] = LOG2E * dot(xw[n,h,:], att[h,:])
__global__ __launch_bounds__(256) void k_gemm1(const float* __restrict__ X,
                                               const f16* __restrict__ W1t,
                                               const float* __restrict__ as1,
                                               const float* __restrict__ ad1,
                                               f16* __restrict__ Af,
                                               float* __restrict__ aS1,
                                               float* __restrict__ aD1, int N) {
    __shared__ f16 sA[64 * 136];
    __shared__ f16 sB[128 * 136];
    const int t = threadIdx.x;
    const int row0 = blockIdx.x * 64;

    {
        int r = t >> 2, seg = t & 3;
        int row = row0 + r;
        if (row >= N) row = N - 1;
        const float4* xg = (const float4*)(X + (size_t)row * 128 + seg * 32);
        unsigned tmp[16];
#pragma unroll
        for (int j = 0; j < 8; j++) {
            float4 v = xg[j];
            tmp[2 * j]     = pack_h2(v.x, v.y);
            tmp[2 * j + 1] = pack_h2(v.z, v.w);
        }
        uint4* dst = (uint4*)&sA[r * 136 + seg * 32];
#pragma unroll
        for (int j = 0; j < 4; j++) dst[j] = ((uint4*)tmp)[j];
        int n = t >> 1, half = (t & 1) * 64;
        const uint4* src = (const uint4*)(W1t + n * 128 + half);
        uint4* dw = (uint4*)&sB[n * 136 + half];
#pragma unroll
        for (int j = 0; j < 8; j++) dw[j] = src[j];
    }
    __syncthreads();

    const int w = t >> 6, lane = t & 63, ln = lane & 15, q = lane >> 4;
    f32x4 acc[8];
#pragma unroll
    for (int c = 0; c < 8; c++) acc[c] = (f32x4){0.f, 0.f, 0.f, 0.f};

#pragma unroll
    for (int ks = 0; ks < 4; ks++) {
        f16x8 a = *(const f16x8*)&sA[(w * 16 + ln) * 136 + ks * 32 + q * 8];
#pragma unroll
        for (int c = 0; c < 8; c++) {
            f16x8 b = *(const f16x8*)&sB[(c * 16 + ln) * 136 + ks * 32 + q * 8];
            acc[c] = __builtin_amdgcn_mfma_f32_16x16x32_f16(a, b, acc[c], 0, 0, 0);
        }
    }

    // store Af
#pragma unroll
    for (int c = 0; c < 8; c++)
#pragma unroll
        for (int reg = 0; reg < 4; reg++) {
            int rg = row0 + w * 16 + q * 4 + reg;
            if (rg < N) Af[(size_t)rg * 128 + c * 16 + ln] = (f16)acc[c][reg];
        }

    // fused attn dots: col = c*16+ln; head h covers cols 32h..32h+31 (c=2h,2h+1)
    float ps[4][4], pd[4][4];   // [h][reg]
#pragma unroll
    for (int h = 0; h < 4; h++) {
        float as_lo = as1[32 * h + ln], as_hi = as1[32 * h + 16 + ln];
        float ad_lo = ad1[32 * h + ln], ad_hi = ad1[32 * h + 16 + ln];
#pragma unroll
        for (int reg = 0; reg < 4; reg++) {
            ps[h][reg] = acc[2 * h][reg] * as_lo + acc[2 * h + 1][reg] * as_hi;
            pd[h][reg] = acc[2 * h][reg] * ad_lo + acc[2 * h + 1][reg] * ad_hi;
        }
    }
#pragma unroll
    for (int h = 0; h < 4; h++)
#pragma unroll
        for (int reg = 0; reg < 4; reg++)
#pragma unroll
            for (int off = 1; off < 16; off <<= 1) {
                ps[h][reg] += __shfl_xor(ps[h][reg], off);
                pd[h][reg] += __shfl_xor(pd[h][reg], off);
            }
#pragma unroll
    for (int h = 0; h < 4; h++) {
        if (ln == 2 * h) {
#pragma unroll
            for (int reg = 0; reg < 4; reg++) {
                int rg = row0 + w * 16 + q * 4 + reg;
                if (rg < N) aS1[rg * 4 + h] = ps[h][reg] * LOG2E;
            }
        }
        if (ln == 2 * h + 1) {
#pragma unroll
            for (int reg = 0; reg < 4; reg++) {
                int rg = row0 + w * 16 + q * 4 + reg;
                if (rg < N) aD1[rg * 4 + h] = pd[h][reg] * LOG2E;
            }
        }
    }
}

// ---------------- GEMM2 (MFMA f16) + fused attn2 dots ----------------
// X2f = (f16)(Hf @ W2) stored PADDED [N][64] (row = one aligned 128B line);
// aS2/aD2[n] = LOG2E * dot(x2[n,:40], att2)
__global__ __launch_bounds__(256) void k_gemm2(const f16* __restrict__ Hf,
                                               const f16* __restrict__ W2t,
                                               const float* __restrict__ as2,
                                               const float* __restrict__ ad2,
                                               f16* __restrict__ X2f,
                                               float* __restrict__ aS2,
                                               float* __restrict__ aD2, int N) {
    __shared__ f16 sA[64 * 136];
    __shared__ f16 sB[48 * 136];
    const int t = threadIdx.x;
    const int row0 = blockIdx.x * 64;
    {
        int r = t >> 2, seg = t & 3;
        int row = row0 + r;
        if (row >= N) row = N - 1;
        const uint4* hg = (const uint4*)(Hf + (size_t)row * 128 + seg * 32);
        uint4* dst = (uint4*)&sA[r * 136 + seg * 32];
#pragma unroll
        for (int j = 0; j < 4; j++) dst[j] = hg[j];
        const uint4* wsrc = (const uint4*)W2t;
#pragma unroll
        for (int u = t; u < 768; u += 256) {
            int o = u * 8;
            int n = o >> 7, ko = o & 127;
            *(uint4*)&sB[n * 136 + ko] = wsrc[u];
        }
    }
    __syncthreads();

    const int w = t >> 6, lane = t & 63, ln = lane & 15, q = lane >> 4;
    f32x4 acc[3];
#pragma unroll
    for (int c = 0; c < 3; c++) acc[c] = (f32x4){0.f, 0.f, 0.f, 0.f};

#pragma unroll
    for (int ks = 0; ks < 4; ks++) {
        f16x8 a = *(const f16x8*)&sA[(w * 16 + ln) * 136 + ks * 32 + q * 8];
#pragma unroll
        for (int c = 0; c < 3; c++) {
            f16x8 b = *(const f16x8*)&sB[(c * 16 + ln) * 136 + ks * 32 + q * 8];
            acc[c] = __builtin_amdgcn_mfma_f32_16x16x32_f16(a, b, acc[c], 0, 0, 0);
        }
    }

#pragma unroll
    for (int c = 0; c < 3; c++) {
        int col = c * 16 + ln;
        if (col < 40) {
#pragma unroll
            for (int reg = 0; reg < 4; reg++) {
                int rg = row0 + w * 16 + q * 4 + reg;
                if (rg < N) X2f[(size_t)rg * 64 + col] = (f16)acc[c][reg];
            }
        } else {
#pragma unroll
            for (int reg = 0; reg < 4; reg++) {
                int rg = row0 + w * 16 + q * 4 + reg;
                if (rg < N) X2f[(size_t)rg * 64 + col] = (f16)0.f;
            }
        }
    }
    {
        int col = 48 + ln;
#pragma unroll
        for (int reg = 0; reg < 4; reg++) {
            int rg = row0 + w * 16 + q * 4 + reg;
            if (rg < N) X2f[(size_t)rg * 64 + col] = (f16)0.f;
        }
    }

    // fused attn dots
    float ps[4], pd[4];
#pragma unroll
    for (int reg = 0; reg < 4; reg++) { ps[reg] = 0.f; pd[reg] = 0.f; }
#pragma unroll
    for (int c = 0; c < 3; c++) {
        int col = c * 16 + ln;
        float as_ = (col < 40) ? as2[col] : 0.f;
        float ad_ = (col < 40) ? ad2[col] : 0.f;
#pragma unroll
        for (int reg = 0; reg < 4; reg++) {
            ps[reg] = fmaf(acc[c][reg], as_, ps[reg]);
            pd[reg] = fmaf(acc[c][reg], ad_, pd[reg]);
        }
    }
#pragma unroll
    for (int reg = 0; reg < 4; reg++) {
#pragma unroll
        for (int off = 1; off < 16; off <<= 1) {
            ps[reg] += __shfl_xor(ps[reg], off);
            pd[reg] += __shfl_xor(pd[reg], off);
        }
        int rg = row0 + w * 16 + q * 4 + reg;
        if (rg < N) {
            if (ln == 0) aS2[rg] = ps[reg] * LOG2E;
            if (ln == 1) aD2[rg] = pd[reg] * LOG2E;
        }
    }
}

// ---------------- fused message + softmax denominator, layer 1 ----------------
// 1 node/wave, 4 waves/block. 4 edge-slots of 16 lanes; each lane covers 8
// channels (dwordx4 gather = one 256 B Af row per slot). First 64 neighbor ids
// bulk-loaded and served via ds_bpermute.
__global__ __launch_bounds__(256) void k_msg1(const int* __restrict__ offsets,
                                              const int* __restrict__ csr_src,
                                              const float* __restrict__ aS,
                                              const float* __restrict__ aD,
                                              const f16* __restrict__ Af,
                                              const float* __restrict__ b1,
                                              f16* __restrict__ Hf, int N) {
    const int lane = threadIdx.x & 63;
    const int n = blockIdx.x * 4 + (threadIdx.x >> 6);
    const bool node_ok = (n < N);
    const int g = lane >> 4;        // edge slot 0..3
    const int p = lane & 15;        // channel group: ch = p*8 .. p*8+7
    const int h = p >> 2;           // head 0..3

    int b = 0, e = 0;
    float adh = 0.f;
    if (node_ok) {
        b = offsets[n];
        e = offsets[n + 1];
        adh = aD[n * 4 + h];
    }

    float acc[8];
#pragma unroll
    for (int k = 0; k < 8; k++) acc[k] = 0.f;
    float wsum = 0.f;

    // self edge: all lanes load row n (broadcast); only slot 0 contributes.
    if (node_ok) {
        float xs = aS[n * 4 + h] + adh;
        float ws = __builtin_amdgcn_exp2f(fmaxf(xs, NEG_SLOPE * xs));
        if (g != 0) ws = 0.f;
        const f16x8 hv = *(const f16x8*)(Af + (size_t)n * 128 + p * 8);
#pragma unroll
        for (int k = 0; k < 8; k++) acc[k] = fmaf(ws, (float)hv[k], acc[k]);
        wsum = ws;
    }

    // preload up to 64 neighbor ids (one per lane)
    int sreg = 0;
    if (node_ok && e > b) {
        int idx = b + lane;
        if (idx >= e) idx = e - 1;
        sreg = csr_src[idx];
    }

    int i = b;
    // main loop: first 64 edges served from registers via bpermute
#pragma unroll 2
    for (; i < e && (i - b) + 4 <= 64; i += 4) {
        int j = i + g;
        bool valid = (j < e);
        int s = __builtin_amdgcn_ds_bpermute((j - b) << 2, sreg);
        if (!valid) s = 0;                               // hot row 0, w=0
        float sv = aS[s * 4 + h];
        const f16x8 hv = *(const f16x8*)(Af + (size_t)s * 128 + p * 8);
        float x = sv + adh;
        float wgt = __builtin_amdgcn_exp2f(fmaxf(x, NEG_SLOPE * x));
        if (!valid) wgt = 0.f;
#pragma unroll
        for (int k = 0; k < 8; k++) acc[k] = fmaf(wgt, (float)hv[k], acc[k]);
        wsum += wgt;
    }
    // residual (deg > 64): direct csr loads
    for (; i < e; i += 4) {
        int j = i + g;
        bool valid = (j < e);
        int jc = valid ? j : (e - 1);
        int s = csr_src[jc];
        if (!valid) s = 0;
        float sv = aS[s * 4 + h];
        const f16x8 hv = *(const f16x8*)(Af + (size_t)s * 128 + p * 8);
        float x = sv + adh;
        float wgt = __builtin_amdgcn_exp2f(fmaxf(x, NEG_SLOPE * x));
        if (!valid) wgt = 0.f;
#pragma unroll
        for (int k = 0; k < 8; k++) acc[k] = fmaf(wgt, (float)hv[k], acc[k]);
        wsum += wgt;
    }

    // reduce across the 4 edge slots (stride-16 lanes)
#pragma unroll
    for (int k = 0; k < 8; k++) {
        acc[k] += __shfl_xor(acc[k], 16);
        acc[k] += __shfl_xor(acc[k], 32);
    }
    wsum += __shfl_xor(wsum, 16);
    wsum += __shfl_xor(wsum, 32);

    if (node_ok && g == 0) {
        float inv = __builtin_amdgcn_rcpf(wsum);
        const float4* bb = (const float4*)(b1 + p * 8);
        float4 b0 = bb[0], b4 = bb[1];
        float bv[8] = {b0.x, b0.y, b0.z, b0.w, b4.x, b4.y, b4.z, b4.w};
        union { f16 h8[8]; uint4 u; } o;
#pragma unroll
        for (int k = 0; k < 8; k++) {
            float v = fmaf(acc[k], inv, bv[k]);
            o.h8[k] = (f16)fmaxf(v, 0.f);
        }
        *(uint4*)(Hf + (size_t)n * 128 + p * 8) = o.u;
    }
}

// ---------------- fused message + softmax denominator, layer 2 ----------------
// 1 node/wave, 4 waves/block. 8 edge-slots of 8 lanes (pow2 shuffle reduce).
// Lane p covers ch p*8..p*8+7 of the PADDED 64-ch row; p>=5 accumulates zeros.
__global__ __launch_bounds__(256) void k_msg2(const int* __restrict__ offsets,
                                              const int* __restrict__ csr_src,
                                              const float* __restrict__ aS,
                                              const float* __restrict__ aD,
                                              const f16* __restrict__ X2f,
                                              const float* __restrict__ b2,
                                              float* __restrict__ OUT, int N) {
    const int lane = threadIdx.x & 63;
    const int n = blockIdx.x * 4 + (threadIdx.x >> 6);
    const bool node_ok = (n < N);
    const int g = lane >> 3;        // edge slot 0..7
    const int p = lane & 7;         // channel group: ch = p*8 .. p*8+7 (p<5 real)

    int b = 0, e = 0;
    float adh = 0.f;
    if (node_ok) {
        b = offsets[n];
        e = offsets[n + 1];
        adh = aD[n];
    }

    float acc[8];
#pragma unroll
    for (int k = 0; k < 8; k++) acc[k] = 0.f;
    float wsum = 0.f;

    // self edge
    if (node_ok) {
        float xs = aS[n] + adh;
        float ws = __builtin_amdgcn_exp2f(fmaxf(xs, NEG_SLOPE * xs));
        if (g != 0) ws = 0.f;
        const f16x8 hv = *(const f16x8*)(X2f + (size_t)n * 64 + p * 8);
#pragma unroll
        for (int k = 0; k < 8; k++) acc[k] = fmaf(ws, (float)hv[k], acc[k]);
        wsum = ws;
    }

    int sreg = 0;
    if (node_ok && e > b) {
        int idx = b + lane;
        if (idx >= e) idx = e - 1;
        sreg = csr_src[idx];
    }

    int i = b;
#pragma unroll 2
    for (; i < e && (i - b) + 8 <= 64; i += 8) {
        int j = i + g;
        bool valid = (j < e);
        int s = __builtin_amdgcn_ds_bpermute((j - b) << 2, sreg);
        if (!valid) s = 0;
        float sv = aS[s];
        const f16x8 hv = *(const f16x8*)(X2f + (size_t)s * 64 + p * 8);
        float x = sv + adh;
        float wgt = __builtin_amdgcn_exp2f(fmaxf(x, NEG_SLOPE * x));
        if (!valid) wgt = 0.f;
#pragma unroll
        for (int k = 0; k < 8; k++) acc[k] = fmaf(wgt, (float)hv[k], acc[k]);
        wsum += wgt;
    }
    for (; i < e; i += 8) {
        int j = i + g;
        bool valid = (j < e);
        int jc = valid ? j : (e - 1);
        int s = csr_src[jc];
        if (!valid) s = 0;
        float sv = aS[s];
        const f16x8 hv = *(const f16x8*)(X2f + (size_t)s * 64 + p * 8);
        float x = sv + adh;
        float wgt = __builtin_amdgcn_exp2f(fmaxf(x, NEG_SLOPE * x));
        if (!valid) wgt = 0.f;
#pragma unroll
        for (int k = 0; k < 8; k++) acc[k] = fmaf(wgt, (float)hv[k], acc[k]);
        wsum += wgt;
    }

#pragma unroll
    for (int k = 0; k < 8; k++) {
        acc[k] += __shfl_xor(acc[k], 8);
        acc[k] += __shfl_xor(acc[k], 16);
        acc[k] += __shfl_xor(acc[k], 32);
    }
    wsum += __shfl_xor(wsum, 8);
    wsum += __shfl_xor(wsum, 16);
    wsum += __shfl_xor(wsum, 32);

    if (node_ok && g == 0 && p < 5) {
        float inv = __builtin_amdgcn_rcpf(wsum);
        const float4* bb = (const float4*)(b2 + p * 8);
        float4 b0 = bb[0], b4 = bb[1];
        float bv[8] = {b0.x, b0.y, b0.z, b0.w, b4.x, b4.y, b4.z, b4.w};
        float4 o0, o1;
        o0.x = fmaf(acc[0], inv, bv[0]); o0.y = fmaf(acc[1], inv, bv[1]);
        o0.z = fmaf(acc[2], inv, bv[2]); o0.w = fmaf(acc[3], inv, bv[3]);
        o1.x = fmaf(acc[4], inv, bv[4]); o1.y = fmaf(acc[5], inv, bv[5]);
        o1.z = fmaf(acc[6], inv, bv[6]); o1.w = fmaf(acc[7], inv, bv[7]);
        float* op = OUT + (size_t)n * 40 + p * 8;
        *(float4*)op = o0;
        *(float4*)(op + 4) = o1;
    }
}

extern "C" void kernel_launch(void* const* d_in, const int* in_sizes, int n_in,
                              void* d_out, int out_size, void* d_ws, size_t ws_size,
                              hipStream_t stream) {
    const float* x   = (const float*)d_in[0];
    const void*  ei  = d_in[1];
    const float* W1  = (const float*)d_in[2];
    const float* as1 = (const float*)d_in[3];
    const float* ad1 = (const float*)d_in[4];
    const float* b1  = (const float*)d_in[5];
    const float* W2  = (const float*)d_in[6];
    const float* as2 = (const float*)d_in[7];
    const float* ad2 = (const float*)d_in[8];
    const float* b2  = (const float*)d_in[9];
    float* out = (float*)d_out;

    const int N = in_sizes[0] / 128;
    const int E = in_sizes[1] / 2;

    // workspace layout — all 16B-aligned
    char* w = (char*)d_ws;
    auto alloc = [&](size_t bytes) {
        char* p = w;
        w += (bytes + 15) & ~(size_t)15;
        return p;
    };
    int* flag        = (int*)alloc(16);
    int* offsets     = (int*)alloc((size_t)(N + 1) * 4);
    int* deg_part    = (int*)alloc((size_t)N * 8 * 4);   // [8][N] sharded histogram
    unsigned* packed = (unsigned*)alloc((size_t)E * 4);  // d<<15 | xcc<<12 | lr
    int* csr_src     = (int*)alloc((size_t)E * 4);
    int* blksum      = (int*)alloc((size_t)CSR_GRID * 4);
    int* blkoff      = (int*)alloc((size_t)CSR_GRID * 4);
    float* aS1       = (float*)alloc((size_t)N * 4 * 4);
    float* aD1       = (float*)alloc((size_t)N * 4 * 4);
    float* aS2       = (float*)alloc((size_t)N * 4);
    float* aD2       = (float*)alloc((size_t)N * 4);
    f16* W1t         = (f16*)alloc(128 * 128 * 2);
    f16* W2t         = (f16*)alloc(48 * 128 * 2);
    f16* Af          = (f16*)alloc((size_t)N * 128 * 2);
    f16* X2f         = (f16*)alloc((size_t)N * 64 * 2); // padded rows (128B lines)
    f16* Hf          = (f16*)alloc((size_t)N * 128 * 2);

    // single cooperative kernel: init + degree + scan + scatter
    {
        const int* ei32 = (const int*)ei;
        const void* eiv = ei;
        int Nv = N, Ev = E;
        void* args[] = {(void*)&ei32, (void*)&eiv, (void*)&flag,
                        (void*)&W1, (void*)&W2, (void*)&W1t, (void*)&W2t,
                        (void*)&deg_part, (void*)&packed, (void*)&offsets,
                        (void*)&blksum, (void*)&blkoff, (void*)&csr_src,
                        (void*)&Nv, (void*)&Ev};
        hipLaunchCooperativeKernel((void*)k_csr, dim3(CSR_GRID), dim3(256),
                                   args, 0, stream);
    }

    // layer 1 (attn fused into gemm)
    const int gb = (N + 63) / 64;
    k_gemm1<<<gb, 256, 0, stream>>>(x, W1t, as1, ad1, Af, aS1, aD1, N);
    k_msg1<<<(N + 3) / 4, 256, 0, stream>>>(offsets, csr_src, aS1, aD1, Af, b1, Hf, N);

    // layer 2 (attn fused into gemm)
    k_gemm2<<<gb, 256, 0, stream>>>(Hf, W2t, as2, ad2, X2f, aS2, aD2, N);
    k_msg2<<<(N + 3) / 4, 256, 0, stream>>>(offsets, csr_src, aS2, aD2, X2f, b2, out, N);
}

// Round 9
// 393.673 us; speedup vs baseline: 2.4833x; 2.4833x over previous
//
#include <hip/hip_runtime.h>
#include <hip/hip_bf16.h>

#define NEG_SLOPE 0.2f
#define LOG2E 1.4426950408889634f
// s_getreg imm: (size-1)<<11 | offset<<6 | id ; HW_REG_XCC_ID = 20 (CDNA3/4)
#define HWREG_XCC_ID_FULL (((32 - 1) << 11) | (0 << 6) | 20)

typedef _Float16 f16;
typedef f16 f16x8 __attribute__((ext_vector_type(8)));
typedef float f32x4 __attribute__((ext_vector_type(4)));

__device__ __forceinline__ unsigned pack_h2(float a, float b) {
    union { f16 h[2]; unsigned u; } c;
    c.h[0] = (f16)a; c.h[1] = (f16)b;
    return c.u;
}

// ---------------- init: detect int64 + weight transpose + deg_part/partials memset ----------------
__global__ void k_init(const int* __restrict__ ei32, int npairs, int* __restrict__ flag,
                       const float* __restrict__ W1, const float* __restrict__ W2,
                       f16* __restrict__ W1t, f16* __restrict__ W2t,
                       uint4* __restrict__ deg_part4, int nzero,
                       int* __restrict__ partials) {
    const int b = blockIdx.x, t = threadIdx.x;
    if (b == 0) {
        __shared__ int found;
        if (t == 0) found = 0;
        if (t < 64) partials[t] = 0;
        __syncthreads();
        for (int i = t; i < npairs; i += 256) {
            if (ei32[2 * i + 1] != 0) found = 1;
        }
        __syncthreads();
        if (t == 0) *flag = found ? 0 : 1;   // 1 => int64
    } else if (b <= 88) {
        int o = (b - 1) * 256 + t;
        if (o < 128 * 128) {
            int n = o >> 7, k = o & 127;
            W1t[o] = (f16)W1[k * 128 + n];
        } else {
            int o2 = o - 128 * 128;
            if (o2 < 48 * 128) {
                int n = o2 >> 7, k = o2 & 127;
                W2t[o2] = (f16)(n < 40 ? W2[k * 40 + n] : 0.f);
            }
        }
    } else {
        int idx = (b - 89) * 256 + t;
        if (idx < nzero) deg_part4[idx] = (uint4){0, 0, 0, 0};
    }
}

// ---------------- CSR build (XCD-sharded histogram), 4 edges/thread ----------------
// packed[e] = d<<15 | xcc<<12 | lr
__global__ void k_degree(const void* __restrict__ ei, const int* __restrict__ flag,
                         int* __restrict__ deg_part, unsigned* __restrict__ packed,
                         int N, int E) {
    const int base = (blockIdx.x * blockDim.x + threadIdx.x) * 4;
    if (base >= E) return;
    const int f64 = *flag;
    const int xcc = (int)(__builtin_amdgcn_s_getreg(HWREG_XCC_ID_FULL) & 7u);
    int dv[4];
    if (f64) {
        const long long* p = (const long long*)ei + E;
#pragma unroll
        for (int k = 0; k < 4; k++) dv[k] = (base + k < E) ? (int)p[base + k] : 0;
    } else {
        const int* p = (const int*)ei + E;
#pragma unroll
        for (int k = 0; k < 4; k++) dv[k] = (base + k < E) ? p[base + k] : 0;
    }
    unsigned pk[4];
#pragma unroll
    for (int k = 0; k < 4; k++) {
        int lr = (base + k < E) ? atomicAdd(&deg_part[xcc * N + dv[k]], 1) : 0;
        pk[k] = ((unsigned)dv[k] << 15) | ((unsigned)xcc << 12) | (unsigned)lr;
    }
#pragma unroll
    for (int k = 0; k < 4; k++)
        if (base + k < E) packed[base + k] = pk[k];
}

// ---------------- single-pass scan: shard-prefix + block scan + lookback ----------------
// Grid = ceil(N/4096) blocks (25 for N=100k) -- all co-resident, so the
// spin-wait lookback cannot deadlock. partials[B] holds total+1 (0 = not ready).
__global__ __launch_bounds__(1024) void k_scan(int* __restrict__ deg_part,
                                               int* __restrict__ offsets,
                                               int* __restrict__ partials, int N) {
    __shared__ int wsums[16];
    __shared__ int bprefix;
    const int t = threadIdx.x;
    const int lane = t & 63;
    const int wid = t >> 6;
    const int B = blockIdx.x;
    int idx = B * 4096 + t * 4;
    int v0 = 0, v1 = 0, v2 = 0, v3 = 0;
    if (((N & 3) == 0) && (idx + 3 < N)) {
        uint4 u[8];
#pragma unroll
        for (int x = 0; x < 8; x++) u[x] = *(uint4*)&deg_part[x * N + idx];
        int p0 = 0, p1 = 0, p2 = 0, p3 = 0;
#pragma unroll
        for (int x = 0; x < 8; x++) {
            uint4 w = u[x];
            u[x] = (uint4){(unsigned)p0, (unsigned)p1, (unsigned)p2, (unsigned)p3};
            p0 += (int)w.x; p1 += (int)w.y; p2 += (int)w.z; p3 += (int)w.w;
        }
#pragma unroll
        for (int x = 0; x < 8; x++) *(uint4*)&deg_part[x * N + idx] = u[x];
        v0 = p0; v1 = p1; v2 = p2; v3 = p3;
    } else if (idx < N) {
        int vv[4] = {0, 0, 0, 0};
        for (int i = 0; i < 4; i++) {
            int d = idx + i;
            if (d >= N) break;
            int p = 0;
#pragma unroll
            for (int x = 0; x < 8; x++) {
                int t0 = deg_part[x * N + d];
                deg_part[x * N + d] = p;
                p += t0;
            }
            vv[i] = p;
        }
        v0 = vv[0]; v1 = vv[1]; v2 = vv[2]; v3 = vv[3];
    }
    const int s1 = v0 + v1, s2 = s1 + v2, s3 = s2 + v3;
    int inc = s3;
#pragma unroll
    for (int off = 1; off < 64; off <<= 1) {
        int y = __shfl_up(inc, off);
        if (lane >= off) inc += y;
    }
    if (lane == 63) wsums[wid] = inc;
    __syncthreads();
    if (wid == 0) {
        int v = (lane < 16) ? wsums[lane] : 0;
        int wi = v;
#pragma unroll
        for (int off = 1; off < 16; off <<= 1) {
            int y = __shfl_up(wi, off);
            if (lane >= off) wi += y;
        }
        if (lane < 16) wsums[lane] = wi - v;
        int tot = __shfl(wi, 15);              // block total (all lanes of wave 0)
        if (lane == 0)
            __hip_atomic_store(&partials[B], tot + 1, __ATOMIC_RELEASE,
                               __HIP_MEMORY_SCOPE_AGENT);
        // lookback: sum totals of all predecessor blocks
        int pre = 0;
        for (int i = lane; i < B; i += 64) {
            int vr;
            do {
                vr = __hip_atomic_load(&partials[i], __ATOMIC_ACQUIRE,
                                       __HIP_MEMORY_SCOPE_AGENT);
            } while (vr == 0);
            pre += vr - 1;
        }
#pragma unroll
        for (int off = 1; off < 64; off <<= 1) pre += __shfl_xor(pre, off);
        if (lane == 0) bprefix = pre;
    }
    __syncthreads();
    const int excl = bprefix + wsums[wid] + (inc - s3);
    if (idx + 0 < N) offsets[idx + 1] = excl + v0;
    if (idx + 1 < N) offsets[idx + 2] = excl + s1;
    if (idx + 2 < N) offsets[idx + 3] = excl + s2;
    if (idx + 3 < N) offsets[idx + 4] = excl + s3;
    if (B == 0 && t == 0) offsets[0] = 0;
}

// scatter: 4 edges/thread; reads contiguous s-column + packed only.
__global__ void k_scatter(const void* __restrict__ ei, const int* __restrict__ flag,
                          const int* __restrict__ offsets, const int* __restrict__ deg_part,
                          const unsigned* __restrict__ packed, int* __restrict__ csr_src,
                          int N, int E) {
    const int base = (blockIdx.x * blockDim.x + threadIdx.x) * 4;
    if (base >= E) return;
    const int f64 = *flag;
    int sv[4];
    if (f64) {
        const long long* p = (const long long*)ei;
#pragma unroll
        for (int k = 0; k < 4; k++) sv[k] = (base + k < E) ? (int)p[base + k] : 0;
    } else {
        const int* p = (const int*)ei;
#pragma unroll
        for (int k = 0; k < 4; k++) sv[k] = (base + k < E) ? p[base + k] : 0;
    }
    unsigned pk[4];
#pragma unroll
    for (int k = 0; k < 4; k++) pk[k] = (base + k < E) ? packed[base + k] : 0;
#pragma unroll
    for (int k = 0; k < 4; k++) {
        if (base + k < E) {
            unsigned u = pk[k];
            int d = (int)(u >> 15);
            int xcc = (int)((u >> 12) & 7u);
            int lr = (int)(u & 0xFFFu);
            csr_src[offsets[d] + deg_part[xcc * N + d] + lr] = sv[k];
        }
    }
}

// ---------------- GEMM1 (MFMA f16) + fused attn1 dots ----------------
__global__ __launch_bounds__(256) void k_gemm1(const float* __restrict__ X,
                                               const f16* __restrict__ W1t,
                                               const float* __restrict__ as1,
                                               const float* __restrict__ ad1,
                                               f16* __restrict__ Af,
                                               float* __restrict__ aS1,
                                               float* __restrict__ aD1, int N) {
    __shared__ f16 sA[64 * 136];
    __shared__ f16 sB[128 * 136];
    const int t = threadIdx.x;
    const int row0 = blockIdx.x * 64;

    {
        int r = t >> 2, seg = t & 3;
        int row = row0 + r;
        if (row >= N) row = N - 1;
        const float4* xg = (const float4*)(X + (size_t)row * 128 + seg * 32);
        unsigned tmp[16];
#pragma unroll
        for (int j = 0; j < 8; j++) {
            float4 v = xg[j];
            tmp[2 * j]     = pack_h2(v.x, v.y);
            tmp[2 * j + 1] = pack_h2(v.z, v.w);
        }
        uint4* dst = (uint4*)&sA[r * 136 + seg * 32];
#pragma unroll
        for (int j = 0; j < 4; j++) dst[j] = ((uint4*)tmp)[j];
        int n = t >> 1, half = (t & 1) * 64;
        const uint4* src = (const uint4*)(W1t + n * 128 + half);
        uint4* dw = (uint4*)&sB[n * 136 + half];
#pragma unroll
        for (int j = 0; j < 8; j++) dw[j] = src[j];
    }
    __syncthreads();

    const int w = t >> 6, lane = t & 63, ln = lane & 15, q = lane >> 4;
    f32x4 acc[8];
#pragma unroll
    for (int c = 0; c < 8; c++) acc[c] = (f32x4){0.f, 0.f, 0.f, 0.f};

#pragma unroll
    for (int ks = 0; ks < 4; ks++) {
        f16x8 a = *(const f16x8*)&sA[(w * 16 + ln) * 136 + ks * 32 + q * 8];
#pragma unroll
        for (int c = 0; c < 8; c++) {
            f16x8 b = *(const f16x8*)&sB[(c * 16 + ln) * 136 + ks * 32 + q * 8];
            acc[c] = __builtin_amdgcn_mfma_f32_16x16x32_f16(a, b, acc[c], 0, 0, 0);
        }
    }

    // store Af
#pragma unroll
    for (int c = 0; c < 8; c++)
#pragma unroll
        for (int reg = 0; reg < 4; reg++) {
            int rg = row0 + w * 16 + q * 4 + reg;
            if (rg < N) Af[(size_t)rg * 128 + c * 16 + ln] = (f16)acc[c][reg];
        }

    // fused attn dots
    float ps[4][4], pd[4][4];   // [h][reg]
#pragma unroll
    for (int h = 0; h < 4; h++) {
        float as_lo = as1[32 * h + ln], as_hi = as1[32 * h + 16 + ln];
        float ad_lo = ad1[32 * h + ln], ad_hi = ad1[32 * h + 16 + ln];
#pragma unroll
        for (int reg = 0; reg < 4; reg++) {
            ps[h][reg] = acc[2 * h][reg] * as_lo + acc[2 * h + 1][reg] * as_hi;
            pd[h][reg] = acc[2 * h][reg] * ad_lo + acc[2 * h + 1][reg] * ad_hi;
        }
    }
#pragma unroll
    for (int h = 0; h < 4; h++)
#pragma unroll
        for (int reg = 0; reg < 4; reg++)
#pragma unroll
            for (int off = 1; off < 16; off <<= 1) {
                ps[h][reg] += __shfl_xor(ps[h][reg], off);
                pd[h][reg] += __shfl_xor(pd[h][reg], off);
            }
#pragma unroll
    for (int h = 0; h < 4; h++) {
        if (ln == 2 * h) {
#pragma unroll
            for (int reg = 0; reg < 4; reg++) {
                int rg = row0 + w * 16 + q * 4 + reg;
                if (rg < N) aS1[rg * 4 + h] = ps[h][reg] * LOG2E;
            }
        }
        if (ln == 2 * h + 1) {
#pragma unroll
            for (int reg = 0; reg < 4; reg++) {
                int rg = row0 + w * 16 + q * 4 + reg;
                if (rg < N) aD1[rg * 4 + h] = pd[h][reg] * LOG2E;
            }
        }
    }
}

// ---------------- GEMM2 (MFMA f16) + fused attn2 dots ----------------
// X2f stored PADDED [N][64] (one 128B line per row; cols 40..63 zeroed)
__global__ __launch_bounds__(256) void k_gemm2(const f16* __restrict__ Hf,
                                               const f16* __restrict__ W2t,
                                               const float* __restrict__ as2,
                                               const float* __restrict__ ad2,
                                               f16* __restrict__ X2f,
                                               float* __restrict__ aS2,
                                               float* __restrict__ aD2, int N) {
    __shared__ f16 sA[64 * 136];
    __shared__ f16 sB[48 * 136];
    const int t = threadIdx.x;
    const int row0 = blockIdx.x * 64;
    {
        int r = t >> 2, seg = t & 3;
        int row = row0 + r;
        if (row >= N) row = N - 1;
        const uint4* hg = (const uint4*)(Hf + (size_t)row * 128 + seg * 32);
        uint4* dst = (uint4*)&sA[r * 136 + seg * 32];
#pragma unroll
        for (int j = 0; j < 4; j++) dst[j] = hg[j];
        const uint4* wsrc = (const uint4*)W2t;
#pragma unroll
        for (int u = t; u < 768; u += 256) {
            int o = u * 8;
            int n = o >> 7, ko = o & 127;
            *(uint4*)&sB[n * 136 + ko] = wsrc[u];
        }
    }
    __syncthreads();

    const int w = t >> 6, lane = t & 63, ln = lane & 15, q = lane >> 4;
    f32x4 acc[3];
#pragma unroll
    for (int c = 0; c < 3; c++) acc[c] = (f32x4){0.f, 0.f, 0.f, 0.f};

#pragma unroll
    for (int ks = 0; ks < 4; ks++) {
        f16x8 a = *(const f16x8*)&sA[(w * 16 + ln) * 136 + ks * 32 + q * 8];
#pragma unroll
        for (int c = 0; c < 3; c++) {
            f16x8 b = *(const f16x8*)&sB[(c * 16 + ln) * 136 + ks * 32 + q * 8];
            acc[c] = __builtin_amdgcn_mfma_f32_16x16x32_f16(a, b, acc[c], 0, 0, 0);
        }
    }

#pragma unroll
    for (int c = 0; c < 3; c++) {
        int col = c * 16 + ln;
        if (col < 40) {
#pragma unroll
            for (int reg = 0; reg < 4; reg++) {
                int rg = row0 + w * 16 + q * 4 + reg;
                if (rg < N) X2f[(size_t)rg * 64 + col] = (f16)acc[c][reg];
            }
        } else {
#pragma unroll
            for (int reg = 0; reg < 4; reg++) {
                int rg = row0 + w * 16 + q * 4 + reg;
                if (rg < N) X2f[(size_t)rg * 64 + col] = (f16)0.f;
            }
        }
    }
    {
        int col = 48 + ln;
#pragma unroll
        for (int reg = 0; reg < 4; reg++) {
            int rg = row0 + w * 16 + q * 4 + reg;
            if (rg < N) X2f[(size_t)rg * 64 + col] = (f16)0.f;
        }
    }

    // fused attn dots
    float ps[4], pd[4];
#pragma unroll
    for (int reg = 0; reg < 4; reg++) { ps[reg] = 0.f; pd[reg] = 0.f; }
#pragma unroll
    for (int c = 0; c < 3; c++) {
        int col = c * 16 + ln;
        float as_ = (col < 40) ? as2[col] : 0.f;
        float ad_ = (col < 40) ? ad2[col] : 0.f;
#pragma unroll
        for (int reg = 0; reg < 4; reg++) {
            ps[reg] = fmaf(acc[c][reg], as_, ps[reg]);
            pd[reg] = fmaf(acc[c][reg], ad_, pd[reg]);
        }
    }
#pragma unroll
    for (int reg = 0; reg < 4; reg++) {
#pragma unroll
        for (int off = 1; off < 16; off <<= 1) {
            ps[reg] += __shfl_xor(ps[reg], off);
            pd[reg] += __shfl_xor(pd[reg], off);
        }
        int rg = row0 + w * 16 + q * 4 + reg;
        if (rg < N) {
            if (ln == 0) aS2[rg] = ps[reg] * LOG2E;
            if (ln == 1) aD2[rg] = pd[reg] * LOG2E;
        }
    }
}

// ---------------- fused message + softmax denominator, layer 1 ----------------
__global__ __launch_bounds__(256) void k_msg1(const int* __restrict__ offsets,
                                              const int* __restrict__ csr_src,
                                              const float* __restrict__ aS,
                                              const float* __restrict__ aD,
                                              const f16* __restrict__ Af,
                                              const float* __restrict__ b1,
                                              f16* __restrict__ Hf, int N) {
    const int lane = threadIdx.x & 63;
    const int n = blockIdx.x * 4 + (threadIdx.x >> 6);
    const bool node_ok = (n < N);
    const int g = lane >> 4;        // edge slot 0..3
    const int p = lane & 15;        // channel group: ch = p*8 .. p*8+7
    const int h = p >> 2;           // head 0..3

    int b = 0, e = 0;
    float adh = 0.f;
    if (node_ok) {
        b = offsets[n];
        e = offsets[n + 1];
        adh = aD[n * 4 + h];
    }

    float acc[8];
#pragma unroll
    for (int k = 0; k < 8; k++) acc[k] = 0.f;
    float wsum = 0.f;

    // self edge
    if (node_ok) {
        float xs = aS[n * 4 + h] + adh;
        float ws = __builtin_amdgcn_exp2f(fmaxf(xs, NEG_SLOPE * xs));
        if (g != 0) ws = 0.f;
        const f16x8 hv = *(const f16x8*)(Af + (size_t)n * 128 + p * 8);
#pragma unroll
        for (int k = 0; k < 8; k++) acc[k] = fmaf(ws, (float)hv[k], acc[k]);
        wsum = ws;
    }

    // preload up to 64 neighbor ids (one per lane)
    int sreg = 0;
    if (node_ok && e > b) {
        int idx = b + lane;
        if (idx >= e) idx = e - 1;
        sreg = csr_src[idx];
    }

    int i = b;
#pragma unroll 2
    for (; i < e && (i - b) + 4 <= 64; i += 4) {
        int j = i + g;
        bool valid = (j < e);
        int s = __builtin_amdgcn_ds_bpermute((j - b) << 2, sreg);
        if (!valid) s = 0;
        float sv = aS[s * 4 + h];
        const f16x8 hv = *(const f16x8*)(Af + (size_t)s * 128 + p * 8);
        float x = sv + adh;
        float wgt = __builtin_amdgcn_exp2f(fmaxf(x, NEG_SLOPE * x));
        if (!valid) wgt = 0.f;
#pragma unroll
        for (int k = 0; k < 8; k++) acc[k] = fmaf(wgt, (float)hv[k], acc[k]);
        wsum += wgt;
    }
    for (; i < e; i += 4) {
        int j = i + g;
        bool valid = (j < e);
        int jc = valid ? j : (e - 1);
        int s = csr_src[jc];
        if (!valid) s = 0;
        float sv = aS[s * 4 + h];
        const f16x8 hv = *(const f16x8*)(Af + (size_t)s * 128 + p * 8);
        float x = sv + adh;
        float wgt = __builtin_amdgcn_exp2f(fmaxf(x, NEG_SLOPE * x));
        if (!valid) wgt = 0.f;
#pragma unroll
        for (int k = 0; k < 8; k++) acc[k] = fmaf(wgt, (float)hv[k], acc[k]);
        wsum += wgt;
    }

#pragma unroll
    for (int k = 0; k < 8; k++) {
        acc[k] += __shfl_xor(acc[k], 16);
        acc[k] += __shfl_xor(acc[k], 32);
    }
    wsum += __shfl_xor(wsum, 16);
    wsum += __shfl_xor(wsum, 32);

    if (node_ok && g == 0) {
        float inv = __builtin_amdgcn_rcpf(wsum);
        const float4* bb = (const float4*)(b1 + p * 8);
        float4 b0 = bb[0], b4 = bb[1];
        float bv[8] = {b0.x, b0.y, b0.z, b0.w, b4.x, b4.y, b4.z, b4.w};
        union { f16 h8[8]; uint4 u; } o;
#pragma unroll
        for (int k = 0; k < 8; k++) {
            float v = fmaf(acc[k], inv, bv[k]);
            o.h8[k] = (f16)fmaxf(v, 0.f);
        }
        *(uint4*)(Hf + (size_t)n * 128 + p * 8) = o.u;
    }
}

// ---------------- fused message + softmax denominator, layer 2 ----------------
// 8 edge-slots of 8 lanes (pow2 shuffle reduce); padded 64-ch rows.
__global__ __launch_bounds__(256) void k_msg2(const int* __restrict__ offsets,
                                              const int* __restrict__ csr_src,
                                              const float* __restrict__ aS,
                                              const float* __restrict__ aD,
                                              const f16* __restrict__ X2f,
                                              const float* __restrict__ b2,
                                              float* __restrict__ OUT, int N) {
    const int lane = threadIdx.x & 63;
    const int n = blockIdx.x * 4 + (threadIdx.x >> 6);
    const bool node_ok = (n < N);
    const int g = lane >> 3;        // edge slot 0..7
    const int p = lane & 7;         // channel group (p<5 real)

    int b = 0, e = 0;
    float adh = 0.f;
    if (node_ok) {
        b = offsets[n];
        e = offsets[n + 1];
        adh = aD[n];
    }

    float acc[8];
#pragma unroll
    for (int k = 0; k < 8; k++) acc[k] = 0.f;
    float wsum = 0.f;

    if (node_ok) {
        float xs = aS[n] + adh;
        float ws = __builtin_amdgcn_exp2f(fmaxf(xs, NEG_SLOPE * xs));
        if (g != 0) ws = 0.f;
        const f16x8 hv = *(const f16x8*)(X2f + (size_t)n * 64 + p * 8);
#pragma unroll
        for (int k = 0; k < 8; k++) acc[k] = fmaf(ws, (float)hv[k], acc[k]);
        wsum = ws;
    }

    int sreg = 0;
    if (node_ok && e > b) {
        int idx = b + lane;
        if (idx >= e) idx = e - 1;
        sreg = csr_src[idx];
    }

    int i = b;
#pragma unroll 2
    for (; i < e && (i - b) + 8 <= 64; i += 8) {
        int j = i + g;
        bool valid = (j < e);
        int s = __builtin_amdgcn_ds_bpermute((j - b) << 2, sreg);
        if (!valid) s = 0;
        float sv = aS[s];
        const f16x8 hv = *(const f16x8*)(X2f + (size_t)s * 64 + p * 8);
        float x = sv + adh;
        float wgt = __builtin_amdgcn_exp2f(fmaxf(x, NEG_SLOPE * x));
        if (!valid) wgt = 0.f;
#pragma unroll
        for (int k = 0; k < 8; k++) acc[k] = fmaf(wgt, (float)hv[k], acc[k]);
        wsum += wgt;
    }
    for (; i < e; i += 8) {
        int j = i + g;
        bool valid = (j < e);
        int jc = valid ? j : (e - 1);
        int s = csr_src[jc];
        if (!valid) s = 0;
        float sv = aS[s];
        const f16x8 hv = *(const f16x8*)(X2f + (size_t)s * 64 + p * 8);
        float x = sv + adh;
        float wgt = __builtin_amdgcn_exp2f(fmaxf(x, NEG_SLOPE * x));
        if (!valid) wgt = 0.f;
#pragma unroll
        for (int k = 0; k < 8; k++) acc[k] = fmaf(wgt, (float)hv[k], acc[k]);
        wsum += wgt;
    }

#pragma unroll
    for (int k = 0; k < 8; k++) {
        acc[k] += __shfl_xor(acc[k], 8);
        acc[k] += __shfl_xor(acc[k], 16);
        acc[k] += __shfl_xor(acc[k], 32);
    }
    wsum += __shfl_xor(wsum, 8);
    wsum += __shfl_xor(wsum, 16);
    wsum += __shfl_xor(wsum, 32);

    if (node_ok && g == 0 && p < 5) {
        float inv = __builtin_amdgcn_rcpf(wsum);
        const float4* bb = (const float4*)(b2 + p * 8);
        float4 b0 = bb[0], b4 = bb[1];
        float bv[8] = {b0.x, b0.y, b0.z, b0.w, b4.x, b4.y, b4.z, b4.w};
        float4 o0, o1;
        o0.x = fmaf(acc[0], inv, bv[0]); o0.y = fmaf(acc[1], inv, bv[1]);
        o0.z = fmaf(acc[2], inv, bv[2]); o0.w = fmaf(acc[3], inv, bv[3]);
        o1.x = fmaf(acc[4], inv, bv[4]); o1.y = fmaf(acc[5], inv, bv[5]);
        o1.z = fmaf(acc[6], inv, bv[6]); o1.w = fmaf(acc[7], inv, bv[7]);
        float* op = OUT + (size_t)n * 40 + p * 8;
        *(float4*)op = o0;
        *(float4*)(op + 4) = o1;
    }
}

extern "C" void kernel_launch(void* const* d_in, const int* in_sizes, int n_in,
                              void* d_out, int out_size, void* d_ws, size_t ws_size,
                              hipStream_t stream) {
    const float* x   = (const float*)d_in[0];
    const void*  ei  = d_in[1];
    const float* W1  = (const float*)d_in[2];
    const float* as1 = (const float*)d_in[3];
    const float* ad1 = (const float*)d_in[4];
    const float* b1  = (const float*)d_in[5];
    const float* W2  = (const float*)d_in[6];
    const float* as2 = (const float*)d_in[7];
    const float* ad2 = (const float*)d_in[8];
    const float* b2  = (const float*)d_in[9];
    float* out = (float*)d_out;

    const int N = in_sizes[0] / 128;
    const int E = in_sizes[1] / 2;

    // workspace layout — all 16B-aligned
    char* w = (char*)d_ws;
    auto alloc = [&](size_t bytes) {
        char* p = w;
        w += (bytes + 15) & ~(size_t)15;
        return p;
    };
    int* flag        = (int*)alloc(16);
    int* offsets     = (int*)alloc((size_t)(N + 1) * 4);
    int* deg_part    = (int*)alloc((size_t)N * 8 * 4);   // [8][N] sharded histogram
    unsigned* packed = (unsigned*)alloc((size_t)E * 4);  // d<<15 | xcc<<12 | lr
    int* csr_src     = (int*)alloc((size_t)E * 4);
    int* partials    = (int*)alloc(64 * 4);
    float* aS1       = (float*)alloc((size_t)N * 4 * 4);
    float* aD1       = (float*)alloc((size_t)N * 4 * 4);
    float* aS2       = (float*)alloc((size_t)N * 4);
    float* aD2       = (float*)alloc((size_t)N * 4);
    f16* W1t         = (f16*)alloc(128 * 128 * 2);
    f16* W2t         = (f16*)alloc(48 * 128 * 2);
    f16* Af          = (f16*)alloc((size_t)N * 128 * 2);
    f16* X2f         = (f16*)alloc((size_t)N * 64 * 2); // padded rows (128B lines)
    f16* Hf          = (f16*)alloc((size_t)N * 128 * 2);

    // init: detect + weight prep + deg_part/partials zero (one launch)
    const int nzero = 2 * N;  // 8N dwords = 2N uint4
    k_init<<<89 + (nzero + 255) / 256, 256, 0, stream>>>(
        (const int*)ei, 1024, flag, W1, W2, W1t, W2t, (uint4*)deg_part, nzero, partials);

    // CSR build: degree -> single-pass scan -> scatter
    k_degree<<<(E + 1023) / 1024, 256, 0, stream>>>(ei, flag, deg_part, packed, N, E);
    const int G = (N + 4095) / 4096;   // 25 blocks for N=100k (co-resident)
    k_scan<<<G, 1024, 0, stream>>>(deg_part, offsets, partials, N);
    k_scatter<<<(E + 1023) / 1024, 256, 0, stream>>>(ei, flag, offsets, deg_part,
                                                     packed, csr_src, N, E);

    // layer 1 (attn fused into gemm)
    const int gb = (N + 63) / 64;
    k_gemm1<<<gb, 256, 0, stream>>>(x, W1t, as1, ad1, Af, aS1, aD1, N);
    k_msg1<<<(N + 3) / 4, 256, 0, stream>>>(offsets, csr_src, aS1, aD1, Af, b1, Hf, N);

    // layer 2 (attn fused into gemm)
    k_gemm2<<<gb, 256, 0, stream>>>(Hf, W2t, as2, ad2, X2f, aS2, aD2, N);
    k_msg2<<<(N + 3) / 4, 256, 0, stream>>>(offsets, csr_src, aS2, aD2, X2f, b2, out, N);
}